// Round 4
// baseline (230.191 us; speedup 1.0000x reference)
//
#include <hip/hip_runtime.h>

// KeyValueMemoryNetwork: B=16, S=2048, C=16, D=256, V=100000
// R8: inline-asm forced 16-deep gather. R6b/R7 both failed to create the
// intended MLP: the compiler sank the table loads into the consume loop
// (VGPR=56/60 vs the >=64 needed for 16 live float4 rows), even across
// sched_barrier(0) — plain loads are IR-movable across the intrinsic.
// Here the 16 loads are asm volatile global_load_dwordx4 (unmovable,
// ordered), with explicit counted s_waitcnt vmcnt(12/8/4/0) +
// sched_barrier(0) fences (the learn_hip rule-#18 pattern) so rows are
// consumed 4-at-a-time while the rest stay in flight.
//   - If latency/MLP-limited: BW 3.2 -> 4.2+ TB/s, dur ~99 -> ~75 us.
//   - If the XCD<->L3/HBM path is saturated (~560 MB/dispatch of L2 misses
//     = 5.7 TB/s demanded): no change -> roofline established.

#define KV_C 16
#define KV_D 256
#define KV_TOKENS (16 * 2048)

typedef float vfloat4 __attribute__((ext_vector_type(4)));

__global__ __launch_bounds__(256, 4) void kv_mem_kernel(
    const int* __restrict__ seq,      // [TOKENS, C] int32
    const float* __restrict__ hidden, // [TOKENS, D]
    const float* __restrict__ table,  // [V, D]
    float* __restrict__ out)          // [TOKENS, D]
{
    const int wave = threadIdx.x >> 6;
    const int lane = threadIdx.x & 63;
    const int token = blockIdx.x * 4 + wave;

    // hidden chunk for this lane (streaming; read once)
    const vfloat4 h = __builtin_nontemporal_load(
        (const vfloat4*)(hidden + (size_t)token * KV_D + lane * 4));

    // lanes 0..15 hold the 16 indices; broadcast via readlane/shuffle
    const int* sp = seq + (size_t)token * KV_C;
    int myidx = (lane < KV_C) ? sp[lane] : 0;
    const unsigned long long nz = __ballot(myidx != 0);

    // Force h to fully retire HERE, so vmcnt below counts ONLY the 16
    // table-row loads (the asm input is a "use" -> compiler emits the wait).
    asm volatile("" :: "v"(h.x), "v"(h.y), "v"(h.z), "v"(h.w));

    // Phase A: 16 table-row loads as volatile asm — genuinely issued
    // back-to-back, 16 KB/wave in flight. ~64 VGPRs for e[] by construction.
    vfloat4 e[KV_C];
    #pragma unroll
    for (int j = 0; j < KV_C; ++j) {
        const int idx = __shfl(myidx, j);   // wave-uniform (readlane)
        const float* p = table + (size_t)idx * KV_D + lane * 4;
        asm volatile("global_load_dwordx4 %0, %1, off"
                     : "=&v"(e[j]) : "v"(p));
    }

    // Phase B: consume 4 rows per counted wait; remaining loads stay in
    // flight. sched_barrier(0) after each wait stops the scheduler from
    // hoisting the dependent FMAs above the wait (rule #18).
    float u[KV_C];
#define KV_CONSUME4(G, NSTR)                                              \
    do {                                                                  \
        asm volatile("s_waitcnt vmcnt(" NSTR ")");                        \
        __builtin_amdgcn_sched_barrier(0);                                \
        _Pragma("unroll")                                                 \
        for (int j = 4 * (G); j < 4 * (G) + 4; ++j) {                     \
            const float msk = ((nz >> j) & 1ULL) ? 1.0f : 0.0f;           \
            u[j] = msk * (h.x * e[j].x + h.y * e[j].y +                   \
                          h.z * e[j].z + h.w * e[j].w);                   \
        }                                                                 \
    } while (0)

    KV_CONSUME4(0, "12");
    KV_CONSUME4(1, "8");
    KV_CONSUME4(2, "4");
    KV_CONSUME4(3, "0");
#undef KV_CONSUME4

    // butterfly-reduce the 16 scores across the 64-lane wave
    #pragma unroll
    for (int s = 32; s >= 1; s >>= 1) {
        #pragma unroll
        for (int j = 0; j < KV_C; ++j) {
            u[j] += __shfl_xor(u[j], s);
        }
    }

    // single-pass softmax (all scores known -> no online rescale)
    float m = u[0];
    #pragma unroll
    for (int j = 1; j < KV_C; ++j) m = fmaxf(m, u[j]);

    float Z = 0.0f;
    #pragma unroll
    for (int j = 0; j < KV_C; ++j) {
        u[j] = __expf(u[j] - m);   // unnormalized weights
        Z += u[j];                 // Z includes padded slots (exp(0-m)), as in ref
    }

    // weighted combine; mask zeroes the padded rows' vectors
    float ox = 0.f, oy = 0.f, oz = 0.f, ow = 0.f;
    #pragma unroll
    for (int j = 0; j < KV_C; ++j) {
        const float msk = ((nz >> j) & 1ULL) ? 1.0f : 0.0f;
        const float wm = u[j] * msk;
        ox += wm * e[j].x;
        oy += wm * e[j].y;
        oz += wm * e[j].z;
        ow += wm * e[j].w;
    }

    const float inv = 1.0f / Z;
    vfloat4 ov;
    ov.x = ox * inv; ov.y = oy * inv; ov.z = oz * inv; ov.w = ow * inv;

    __builtin_nontemporal_store(ov,
        (vfloat4*)(out + (size_t)token * KV_D + lane * 4));
}

extern "C" void kernel_launch(void* const* d_in, const int* in_sizes, int n_in,
                              void* d_out, int out_size, void* d_ws, size_t ws_size,
                              hipStream_t stream) {
    const int*   seq    = (const int*)d_in[0];
    const float* hidden = (const float*)d_in[1];
    const float* table  = (const float*)d_in[2];
    float*       out    = (float*)d_out;

    dim3 grid(KV_TOKENS / 4);   // 8192 blocks, 4 waves (tokens) per block
    dim3 block(256);
    kv_mem_kernel<<<grid, block, 0, stream>>>(seq, hidden, table, out);
}